// Round 14
// baseline (198.587 us; speedup 1.0000x reference)
//
#include <hip/hip_runtime.h>
#include <hip/hip_bf16.h>
#include <cstdint>

namespace {
constexpr int H_  = 1536;
constexpr int NH_ = 24;
constexpr int HD_ = 64;
constexpr int B_  = 2;
constexpr int S_  = 2048;
constexpr int M_  = B_ * S_;          // 4096
constexpr int KD_ = H_;               // GEMM depth
}

typedef __attribute__((ext_vector_type(8)))  short bf16x8;
typedef __attribute__((ext_vector_type(4)))  float f32x4;
typedef __attribute__((ext_vector_type(16))) float f32x16;

// fp32 -> bf16, round-half-up (2 VALU ops; vs ~5 for RNE emulation)
__device__ __forceinline__ unsigned short f2bf_fast(float x) {
    return (unsigned short)((__float_as_uint(x) + 0x8000u) >> 16);
}
// two fp32 -> packed bf16x2 in a u32 (lo = a, hi = b), round-half-up
__device__ __forceinline__ unsigned pack2bf(float b_hi, float a_lo) {
    const unsigned ub = __float_as_uint(b_hi) + 0x8000u;
    const unsigned ua = __float_as_uint(a_lo) + 0x8000u;
    return (ub & 0xffff0000u) | (ua >> 16);
}
// two fp32 -> packed bf16x2, single HW instr, RNE (T12: no builtin on gfx950)
__device__ __forceinline__ unsigned cvt_pk_bf16(float lo, float hi) {
    unsigned r;
    asm("v_cvt_pk_bf16_f32 %0, %1, %2" : "=v"(r) : "v"(lo), "v"(hi));
    return r;
}

__device__ __forceinline__ float fast_exp2(float x) {
#if __has_builtin(__builtin_amdgcn_exp2f)
    return __builtin_amdgcn_exp2f(x);   // bare v_exp_f32
#else
    return exp2f(x);
#endif
}

__device__ __forceinline__ void gload16(const short* g, short* l) {
    __builtin_amdgcn_global_load_lds(
        (const __attribute__((address_space(1))) unsigned int*)g,
        (__attribute__((address_space(3))) unsigned int*)l, 16, 0, 0);
}

// ---------------------------------------------------------------------------
// Fused fp32 -> bf16 cast for X and the 4 weight matrices (one launch).
// ---------------------------------------------------------------------------
__global__ __launch_bounds__(256)
void cast_all(const float* __restrict__ X,
              const float* __restrict__ wq, const float* __restrict__ wk,
              const float* __restrict__ wv, const float* __restrict__ wo,
              short* __restrict__ Xh,
              short* __restrict__ Wqh, short* __restrict__ Wkh,
              short* __restrict__ Wvh, short* __restrict__ Woh)
{
    constexpr int XB = (M_*H_) / 1024;   // 6144 blocks for X
    constexpr int WB = (H_*H_) / 1024;   // 2304 blocks per weight
    const int bid = blockIdx.x;
    const float* src; short* dst; int off;
    if (bid < XB)            { src = X;  dst = Xh;  off = bid; }
    else {
        const int r = bid - XB, wsel = r / WB; off = r % WB;
        if      (wsel == 0)  { src = wq; dst = Wqh; }
        else if (wsel == 1)  { src = wk; dst = Wkh; }
        else if (wsel == 2)  { src = wv; dst = Wvh; }
        else                 { src = wo; dst = Woh; }
    }
    const int i = (off * 256 + threadIdx.x) * 4;
    const float4 v = *(const float4*)&src[i];
    uint2 o;
    o.x = pack2bf(v.y, v.x);
    o.y = pack2bf(v.w, v.z);
    *(uint2*)&dst[i] = o;
}

// ---------------------------------------------------------------------------
// bf16 GEMM (single pass):  C[M,N] = A[M,K] @ W[N,K]^T + bias, fp32 accum.
// R14: tile 256x64 (was 128x128).  Same 64x64 per-wave microtile — 4 waves
// split m 4-ways and SHARE the one 64-col B tile (B LDS reads are wave-
// uniform broadcasts = free).  Rationale: R13's FETCH=69.7MB = X(12.6) +
// 4x weights(14.2) — each weight tile was read by 4 m-blocks per XCD from
// L3 (13.8MB weight set >> 4MB L2).  BM=256 halves that to 2x.  LDS 40 KB
// -> 4 blocks/CU.  BK=64, 2 barriers/K-step, global_load_lds w16 with
// inverse XOR swizzle on the GLOBAL source (rule 21); conflict-free reads.
// KIND 0 (QKV fused, grid 1152): z=0 Q (rope, scale=0.125*log2e), z=1 K
// (rope), z=2 V (bf16 transposed (b,h,d,s)).  KIND 1 (O-proj, grid 384).
// n-tile (64) = exactly one head -> epilogue formulas unchanged (wc -> 0).
// Bijective XCD decode: 2 m-tiles per XCD -> X stays L2-resident.
// ---------------------------------------------------------------------------
template<int KIND>
__global__ __launch_bounds__(256, 4)
void gemm_bf16(const short* __restrict__ A_g,
               const short* __restrict__ Wq, const short* __restrict__ Wk,
               const short* __restrict__ Wv,
               const float* __restrict__ bq, const float* __restrict__ bk,
               const float* __restrict__ bv,
               const float* __restrict__ cosb, const float* __restrict__ sinb,
               short* __restrict__ Qb, short* __restrict__ Kb,
               short* __restrict__ Vt, float* __restrict__ outf)
{
    __shared__ short Ah[256*64];   // 32 KB
    __shared__ short Bh[64*64];    //  8 KB

    const int t    = threadIdx.x;
    const int lane = t & 63;
    const int w    = t >> 6;        // wave 0..3 = which 64-row m-stripe
    const int l15  = lane & 15;
    const int grp  = lane >> 4;

    // bijective XCD-aware decode: m fast (2 per XCD), then n, then z
    const int xcd = blockIdx.x & 7;
    const int off = blockIdx.x >> 3;
    const int m_idx = xcd * 2 + (off & 1);       // 0..15
    const int rest  = off >> 1;                  // QKV: 0..71, O: 0..23
    const int n_idx = rest % 24;
    const int zi    = (KIND == 0) ? rest / 24 : 3;

    const int m0 = m_idx * 256;
    const int n0 = n_idx * 64;

    const short* bhg; const float* bias;
    if (KIND == 0) {
        if      (zi == 0) { bhg = Wq; bias = bq; }
        else if (zi == 1) { bhg = Wk; bias = bk; }
        else              { bhg = Wv; bias = bv; }
    } else {
        bhg = Wq; bias = bq;                     // O-proj passes wo/bo here
    }

    f32x4 acc[4][4];
#pragma unroll
    for (int i = 0; i < 4; ++i)
#pragma unroll
        for (int j = 0; j < 4; ++j) acc[i][j] = (f32x4){0.f, 0.f, 0.f, 0.f};

    const int srow  = lane >> 3;
    const int sslot = (lane & 7) ^ srow;

    for (int kt = 0; kt < KD_; kt += 64) {
        __syncthreads();
        // A: 32 chunks (8 rows x 64B each); wave w stages chunks w*8..w*8+7
#pragma unroll
        for (int cc = 0; cc < 8; ++cc) {
            const int c = w * 8 + cc;
            const int r = c * 8 + srow;
            gload16(A_g + (size_t)(m0 + r) * KD_ + kt + sslot * 8, Ah + c * 512);
        }
        // B: 8 chunks; wave w stages chunks w*2, w*2+1
#pragma unroll
        for (int cc = 0; cc < 2; ++cc) {
            const int c = w * 2 + cc;
            const int r = c * 8 + srow;
            gload16(bhg + (size_t)(n0 + r) * KD_ + kt + sslot * 8, Bh + c * 512);
        }
        __syncthreads();

#pragma unroll
        for (int kk = 0; kk < 2; ++kk) {
            bf16x8 af[4], bfr[4];
#pragma unroll
            for (int i = 0; i < 4; ++i) {
                const int ra = w * 64 + i * 16 + l15;
                af[i]  = *(const bf16x8*)&Ah[ra * 64 + (((kk*4 + grp) ^ (ra & 7)) << 3)];
                const int rb = i * 16 + l15;
                bfr[i] = *(const bf16x8*)&Bh[rb * 64 + (((kk*4 + grp) ^ (rb & 7)) << 3)];
            }
#pragma unroll
            for (int i = 0; i < 4; ++i)
#pragma unroll
                for (int j = 0; j < 4; ++j)
                    acc[i][j] = __builtin_amdgcn_mfma_f32_16x16x32_bf16(af[i], bfr[j], acc[i][j], 0, 0, 0);
        }
    }

    // ---------------- epilogue ----------------
    float bn[4];
#pragma unroll
    for (int ni = 0; ni < 4; ++ni) bn[ni] = bias[n0 + ni * 16 + l15];
    const int hw = n0 >> 6;                      // head (= n_idx)

    if (KIND == 1) {
#pragma unroll
        for (int mi = 0; mi < 4; ++mi)
#pragma unroll
            for (int r = 0; r < 4; ++r) {
                const int m = m0 + w * 64 + mi * 16 + grp * 4 + r;
#pragma unroll
                for (int ni = 0; ni < 4; ++ni)
                    outf[(size_t)m * H_ + n0 + ni * 16 + l15] =
                        acc[mi][ni][r] + bn[ni];
            }
        return;
    }

    if (zi == 2) {
        // V: bf16 transposed (b, h, d, s)
        const int b = m0 >> 11;
#pragma unroll
        for (int mi = 0; mi < 4; ++mi) {
            const int sb = (m0 & (S_ - 1)) + w * 64 + mi * 16 + grp * 4;
#pragma unroll
            for (int ni = 0; ni < 4; ++ni) {
                const int d = ni * 16 + l15;
                uint2 o;
                o.x = pack2bf(acc[mi][ni][1] + bn[ni], acc[mi][ni][0] + bn[ni]);
                o.y = pack2bf(acc[mi][ni][3] + bn[ni], acc[mi][ni][2] + bn[ni]);
                *(uint2*)&Vt[((size_t)(b * NH_ + hw) * HD_ + d) * S_ + sb] = o;
            }
        }
        return;
    }

    // Q/K: rope + scale + bf16 head-major (b,h,s,d); partner d^32 = acc[..][ni^2]
    // Q carries 0.125*log2(e) so attention scores are already in exp2 domain.
    const float sc = (zi == 0) ? 0.18033688011112042f : 1.0f;
    short* dst = (zi == 0) ? Qb : Kb;
#pragma unroll
    for (int mi = 0; mi < 4; ++mi)
#pragma unroll
        for (int r = 0; r < 4; ++r) {
            const int m = m0 + w * 64 + mi * 16 + grp * 4 + r;
            const int b = m >> 11;
            const int s = m & (S_ - 1);
#pragma unroll
            for (int ni = 0; ni < 4; ++ni) {
                const int d  = ni * 16 + l15;
                const float val = acc[mi][ni][r] + bn[ni];
                const float pv  = acc[mi][ni ^ 2][r] + bn[ni ^ 2];
                const float cs = cosb[s * HD_ + d];
                const float sn = sinb[s * HD_ + d];
                const float rot = (ni < 2) ? -pv : pv;
                dst[((size_t)(b * NH_ + hw) * S_ + s) * HD_ + d] =
                    (short)f2bf_fast((val * cs + rot * sn) * sc);
            }
        }
}

// ---------------------------------------------------------------------------
// Flash attention, bf16 MFMA 32x32x16, fp32 accum, non-causal.
// (R13 kernel, unchanged: XCD-affine map, LDS staging, in-register P via
// cvt_pk_bf16 + permlane32_swap, fixed-max exp2 softmax, 4-way parallel
// deferred denominator.)
// ---------------------------------------------------------------------------
__global__ __launch_bounds__(256, 3)
void attn_mfma(const short* __restrict__ Q, const short* __restrict__ K,
               const short* __restrict__ Vt, short* __restrict__ AO)
{
    __shared__ short Ks[2][4096];    // [kv=64][d=64] swizzled, 8 KB per buf
    __shared__ short Vs[2][4096];    // [d=64][kv=64] swizzled, 8 KB per buf

    const int t    = threadIdx.x;
    const int lane = t & 63;
    const int wid  = t >> 6;         // 0..3

    const int bid = blockIdx.x;
    const int xcd = bid & 7;
    const int sq  = bid >> 3;            // 0..95
    const int bh  = xcd * 6 + (sq >> 4); // 0..47
    const int q0  = (sq & 15) * 128;

    const int l31 = lane & 31;
    const int hi  = lane >> 5;
    const int sw7 = lane & 7;

    const short* Qg = Q  + ((size_t)bh * S_ + q0 + wid*32) * HD_;
    const short* Kg = K  + (size_t)bh * S_ * HD_;
    const short* Vg = Vt + (size_t)bh * HD_ * S_;

    bf16x8 qf[4];
#pragma unroll
    for (int kk = 0; kk < 4; ++kk)
        qf[kk] = *(const bf16x8*)(Qg + (size_t)l31*HD_ + kk*16 + hi*8);

    f32x16 oacc[2];
#pragma unroll
    for (int nt = 0; nt < 2; ++nt)
#pragma unroll
        for (int r = 0; r < 16; ++r) oacc[nt][r] = 0.f;
    float la[4] = {0.f, 0.f, 0.f, 0.f};

    auto stageKV = [&](int b, int kt) {
#pragma unroll
        for (int cc = 0; cc < 2; ++cc) {
            const int d   = cc * 256 + t;
            const int row = d >> 3;
            const int sg  = (d & 7) ^ (row & 7);
            gload16(Kg + (size_t)(kt + row) * HD_ + sg * 8, &Ks[b][d * 8]);
            gload16(Vg + (size_t)row * S_ + kt + sg * 8,    &Vs[b][d * 8]);
        }
    };

    stageKV(0, 0);
    __syncthreads();
    int cur = 0;

    for (int kt = 0; kt < S_; kt += 64) {
        if (kt + 64 < S_) stageKV(cur ^ 1, kt + 64);

        f32x16 sac[2];
#pragma unroll
        for (int nt = 0; nt < 2; ++nt)
#pragma unroll
            for (int r = 0; r < 16; ++r) sac[nt][r] = 0.f;
        __builtin_amdgcn_s_setprio(1);
#pragma unroll
        for (int kk = 0; kk < 4; ++kk) {
#pragma unroll
            for (int nt = 0; nt < 2; ++nt) {
                const int row = nt*32 + l31;
                const bf16x8 kfrag = *(const bf16x8*)
                    &Ks[cur][row*64 + (((kk*2 + hi) ^ sw7) << 3)];
                sac[nt] = __builtin_amdgcn_mfma_f32_32x32x16_bf16(kfrag, qf[kk], sac[nt], 0, 0, 0);
            }
        }
        __builtin_amdgcn_s_setprio(0);

#pragma unroll
        for (int nt = 0; nt < 2; ++nt)
#pragma unroll
            for (int r = 0; r < 16; ++r) {
                sac[nt][r] = fast_exp2(sac[nt][r]);
                la[r & 3] += sac[nt][r];
            }

        unsigned pw[4][4];
#pragma unroll
        for (int kk = 0; kk < 4; ++kk) {
            const int h  = kk >> 1;
            const int g2 = (kk & 1) * 2;
#pragma unroll
            for (int e = 0; e < 2; ++e) {
                unsigned A = cvt_pk_bf16(sac[h][4*g2     + 2*e], sac[h][4*g2     + 2*e + 1]);
                unsigned Bv= cvt_pk_bf16(sac[h][4*(g2+1) + 2*e], sac[h][4*(g2+1) + 2*e + 1]);
                asm volatile("v_permlane32_swap_b32 %0, %1" : "+v"(A), "+v"(Bv));
                pw[kk][e]     = A;
                pw[kk][e + 2] = Bv;
            }
        }

        __builtin_amdgcn_s_setprio(1);
#pragma unroll
        for (int ks = 0; ks < 4; ++ks) {
            union { unsigned u[4]; bf16x8 v; } pf;
            pf.u[0] = pw[ks][0]; pf.u[1] = pw[ks][1];
            pf.u[2] = pw[ks][2]; pf.u[3] = pw[ks][3];
#pragma unroll
            for (int nt = 0; nt < 2; ++nt) {
                const int row = nt*32 + l31;
                const bf16x8 vfrag = *(const bf16x8*)
                    &Vs[cur][row*64 + (((ks*2 + hi) ^ sw7) << 3)];
                oacc[nt] = __builtin_amdgcn_mfma_f32_32x32x16_bf16(vfrag, pf.v, oacc[nt], 0, 0, 0);
            }
        }
        __builtin_amdgcn_s_setprio(0);

        __syncthreads();
        cur ^= 1;
    }

    float lacc = (la[0] + la[1]) + (la[2] + la[3]);
    lacc += __shfl_xor(lacc, 32);
    const float inv = 1.f / lacc;

    const int b = bh / NH_, h = bh % NH_;
    const int srow = q0 + wid*32 + l31;
    const size_t rowb = ((size_t)(b*S_ + srow)) * H_ + h*HD_;
#pragma unroll
    for (int nt = 0; nt < 2; ++nt)
#pragma unroll
        for (int i = 0; i < 8; ++i) {
            const int crow = ((2*i) & 3) + 8*((2*i) >> 2) + 4*hi;
            const int d    = nt*32 + crow;
            *(unsigned*)&AO[rowb + d] =
                cvt_pk_bf16(oacc[nt][2*i]*inv, oacc[nt][2*i+1]*inv);
        }
}

// ---------------------------------------------------------------------------
extern "C" void kernel_launch(void* const* d_in, const int* in_sizes, int n_in,
                              void* d_out, int out_size, void* d_ws, size_t ws_size,
                              hipStream_t stream)
{
    const float* X    = (const float*)d_in[0];
    const float* cosb = (const float*)d_in[1];
    const float* sinb = (const float*)d_in[2];
    const float* wq   = (const float*)d_in[3];
    const float* bq   = (const float*)d_in[4];
    const float* wk   = (const float*)d_in[5];
    const float* bk   = (const float*)d_in[6];
    const float* wv   = (const float*)d_in[7];
    const float* bv   = (const float*)d_in[8];
    const float* wo   = (const float*)d_in[9];
    const float* bo   = (const float*)d_in[10];
    float* out = (float*)d_out;

    const size_t MH = (size_t)M_ * H_;      // 6.29M
    const size_t HH = (size_t)H_ * H_;      // 2.36M

    short* Xh  = (short*)d_ws;
    short* Wqh = Xh  + MH;
    short* Wkh = Wqh + HH;
    short* Wvh = Wkh + HH;
    short* Woh = Wvh + HH;
    short* Qb  = Woh + HH;
    short* Kb  = Qb + MH;
    short* Vt  = Kb + MH;
    short* AO  = Vt + MH;

    cast_all<<<(int)(MH/1024 + 4*(HH/1024)), 256, 0, stream>>>(
        X, wq, wk, wv, wo, Xh, Wqh, Wkh, Wvh, Woh);

    gemm_bf16<0><<<1152, 256, 0, stream>>>(Xh, Wqh, Wkh, Wvh,
        bq, bk, bv, cosb, sinb, Qb, Kb, Vt, nullptr);

    attn_mfma<<<768, 256, 0, stream>>>(Qb, Kb, Vt, AO);

    gemm_bf16<1><<<384, 256, 0, stream>>>(AO, Woh, nullptr, nullptr,
        bo, nullptr, nullptr, nullptr, nullptr, nullptr, nullptr, nullptr, out);
}

// Round 15
// 191.423 us; speedup vs baseline: 1.0374x; 1.0374x over previous
//
#include <hip/hip_runtime.h>
#include <hip/hip_bf16.h>
#include <cstdint>

namespace {
constexpr int H_  = 1536;
constexpr int NH_ = 24;
constexpr int HD_ = 64;
constexpr int B_  = 2;
constexpr int S_  = 2048;
constexpr int M_  = B_ * S_;          // 4096
constexpr int KD_ = H_;               // GEMM depth
}

typedef __attribute__((ext_vector_type(8)))  short bf16x8;
typedef __attribute__((ext_vector_type(4)))  float f32x4;
typedef __attribute__((ext_vector_type(16))) float f32x16;

// fp32 -> bf16, round-half-up (2 VALU ops; vs ~5 for RNE emulation)
__device__ __forceinline__ unsigned short f2bf_fast(float x) {
    return (unsigned short)((__float_as_uint(x) + 0x8000u) >> 16);
}
// two fp32 -> packed bf16x2 in a u32 (lo = a, hi = b), round-half-up
__device__ __forceinline__ unsigned pack2bf(float b_hi, float a_lo) {
    const unsigned ub = __float_as_uint(b_hi) + 0x8000u;
    const unsigned ua = __float_as_uint(a_lo) + 0x8000u;
    return (ub & 0xffff0000u) | (ua >> 16);
}
// two fp32 -> packed bf16x2, single HW instr, RNE (T12: no builtin on gfx950)
__device__ __forceinline__ unsigned cvt_pk_bf16(float lo, float hi) {
    unsigned r;
    asm("v_cvt_pk_bf16_f32 %0, %1, %2" : "=v"(r) : "v"(lo), "v"(hi));
    return r;
}

__device__ __forceinline__ float fast_exp2(float x) {
#if __has_builtin(__builtin_amdgcn_exp2f)
    return __builtin_amdgcn_exp2f(x);   // bare v_exp_f32
#else
    return exp2f(x);
#endif
}

__device__ __forceinline__ void gload16(const short* g, short* l) {
    __builtin_amdgcn_global_load_lds(
        (const __attribute__((address_space(1))) unsigned int*)g,
        (__attribute__((address_space(3))) unsigned int*)l, 16, 0, 0);
}

// ---------------------------------------------------------------------------
// Fused fp32 -> bf16 cast for X and the 4 weight matrices (one launch).
// ---------------------------------------------------------------------------
__global__ __launch_bounds__(256)
void cast_all(const float* __restrict__ X,
              const float* __restrict__ wq, const float* __restrict__ wk,
              const float* __restrict__ wv, const float* __restrict__ wo,
              short* __restrict__ Xh,
              short* __restrict__ Wqh, short* __restrict__ Wkh,
              short* __restrict__ Wvh, short* __restrict__ Woh)
{
    constexpr int XB = (M_*H_) / 1024;   // 6144 blocks for X
    constexpr int WB = (H_*H_) / 1024;   // 2304 blocks per weight
    const int bid = blockIdx.x;
    const float* src; short* dst; int off;
    if (bid < XB)            { src = X;  dst = Xh;  off = bid; }
    else {
        const int r = bid - XB, wsel = r / WB; off = r % WB;
        if      (wsel == 0)  { src = wq; dst = Wqh; }
        else if (wsel == 1)  { src = wk; dst = Wkh; }
        else if (wsel == 2)  { src = wv; dst = Wvh; }
        else                 { src = wo; dst = Woh; }
    }
    const int i = (off * 256 + threadIdx.x) * 4;
    const float4 v = *(const float4*)&src[i];
    uint2 o;
    o.x = pack2bf(v.y, v.x);
    o.y = pack2bf(v.w, v.z);
    *(uint2*)&dst[i] = o;
}

// ---------------------------------------------------------------------------
// bf16 GEMM (single pass):  C[M,N] = A[M,K] @ W[N,K]^T + bias, fp32 accum.
// R15: REVERTED to the R13 128x128 config (proven 74us; R14's BM=256 was
// staging-throughput-bound, +25% staged bytes/output -> +23% dur, FETCH
// unchanged).  m97-style: BK=64, single-buffered 32 KB LDS, 2 barriers per
// K-step, global_load_lds w16, inverse XOR swizzle on the GLOBAL source.
// KIND 0 (QKV fused, grid 1152): z=0 Q (rope, scale=0.125*log2e), z=1 K
// (rope), z=2 V (bf16 transposed (b,h,d,s)).  KIND 1 (O-proj): fp32 + bias.
// ---------------------------------------------------------------------------
template<int KIND>
__global__ __launch_bounds__(256, 4)
void gemm_bf16(const short* __restrict__ A_g,
               const short* __restrict__ Wq, const short* __restrict__ Wk,
               const short* __restrict__ Wv,
               const float* __restrict__ bq, const float* __restrict__ bk,
               const float* __restrict__ bv,
               const float* __restrict__ cosb, const float* __restrict__ sinb,
               short* __restrict__ Qb, short* __restrict__ Kb,
               short* __restrict__ Vt, float* __restrict__ outf)
{
    __shared__ short Ah[128*64], Bh[128*64];   // 16 KB each

    const int t    = threadIdx.x;
    const int lane = t & 63;
    const int w    = t >> 6;
    const int wr   = w >> 1, wc = w & 1;
    const int l15  = lane & 15;
    const int grp  = lane >> 4;

    // bijective XCD-aware decode: m fast (4 per XCD), then n, then z
    const int xcd = blockIdx.x & 7;
    const int off = blockIdx.x >> 3;
    const int m_idx = xcd * 4 + (off & 3);
    const int rest  = off >> 2;                  // QKV: 0..35, O: 0..11
    const int n_idx = rest % 12;
    const int zi    = (KIND == 0) ? rest / 12 : 3;

    const int m0 = m_idx * 128;
    const int n0 = n_idx * 128;

    const short* bhg; const float* bias;
    if (KIND == 0) {
        if      (zi == 0) { bhg = Wq; bias = bq; }
        else if (zi == 1) { bhg = Wk; bias = bk; }
        else              { bhg = Wv; bias = bv; }
    } else {
        bhg = Wq; bias = bq;                     // O-proj passes wo/bo here
    }

    f32x4 acc[4][4];
#pragma unroll
    for (int i = 0; i < 4; ++i)
#pragma unroll
        for (int j = 0; j < 4; ++j) acc[i][j] = (f32x4){0.f, 0.f, 0.f, 0.f};

    const int srow  = lane >> 3;
    const int sslot = (lane & 7) ^ srow;

    for (int kt = 0; kt < KD_; kt += 64) {
        __syncthreads();
#pragma unroll
        for (int cc = 0; cc < 4; ++cc) {
            const int c = w * 4 + cc;
            const int r = c * 8 + srow;
            gload16(A_g + (size_t)(m0 + r) * KD_ + kt + sslot * 8, Ah + c * 512);
            gload16(bhg + (size_t)(n0 + r) * KD_ + kt + sslot * 8, Bh + c * 512);
        }
        __syncthreads();

#pragma unroll
        for (int kk = 0; kk < 2; ++kk) {
            bf16x8 af[4], bfr[4];
#pragma unroll
            for (int i = 0; i < 4; ++i) {
                const int ra = wr * 64 + i * 16 + l15;
                af[i]  = *(const bf16x8*)&Ah[ra * 64 + (((kk*4 + grp) ^ (ra & 7)) << 3)];
                const int rb = wc * 64 + i * 16 + l15;
                bfr[i] = *(const bf16x8*)&Bh[rb * 64 + (((kk*4 + grp) ^ (rb & 7)) << 3)];
            }
#pragma unroll
            for (int i = 0; i < 4; ++i)
#pragma unroll
                for (int j = 0; j < 4; ++j)
                    acc[i][j] = __builtin_amdgcn_mfma_f32_16x16x32_bf16(af[i], bfr[j], acc[i][j], 0, 0, 0);
        }
    }

    // ---------------- epilogue ----------------
    float bn[4];
#pragma unroll
    for (int ni = 0; ni < 4; ++ni) bn[ni] = bias[n0 + wc * 64 + ni * 16 + l15];
    const int hw = (n0 + wc * 64) >> 6;          // head (tile 64-aligned)

    if (KIND == 1) {
#pragma unroll
        for (int mi = 0; mi < 4; ++mi)
#pragma unroll
            for (int r = 0; r < 4; ++r) {
                const int m = m0 + wr * 64 + mi * 16 + grp * 4 + r;
#pragma unroll
                for (int ni = 0; ni < 4; ++ni)
                    outf[(size_t)m * H_ + n0 + wc * 64 + ni * 16 + l15] =
                        acc[mi][ni][r] + bn[ni];
            }
        return;
    }

    if (zi == 2) {
        // V: bf16 transposed (b, h, d, s)
        const int b = m0 >> 11;
#pragma unroll
        for (int mi = 0; mi < 4; ++mi) {
            const int sb = (m0 & (S_ - 1)) + wr * 64 + mi * 16 + grp * 4;
#pragma unroll
            for (int ni = 0; ni < 4; ++ni) {
                const int d = ni * 16 + l15;
                uint2 o;
                o.x = pack2bf(acc[mi][ni][1] + bn[ni], acc[mi][ni][0] + bn[ni]);
                o.y = pack2bf(acc[mi][ni][3] + bn[ni], acc[mi][ni][2] + bn[ni]);
                *(uint2*)&Vt[((size_t)(b * NH_ + hw) * HD_ + d) * S_ + sb] = o;
            }
        }
        return;
    }

    // Q/K: rope + scale + bf16 head-major (b,h,s,d); partner d^32 = acc[..][ni^2]
    // Q carries 0.125*log2(e) so attention scores are already in exp2 domain.
    const float sc = (zi == 0) ? 0.18033688011112042f : 1.0f;
    short* dst = (zi == 0) ? Qb : Kb;
#pragma unroll
    for (int mi = 0; mi < 4; ++mi)
#pragma unroll
        for (int r = 0; r < 4; ++r) {
            const int m = m0 + wr * 64 + mi * 16 + grp * 4 + r;
            const int b = m >> 11;
            const int s = m & (S_ - 1);
#pragma unroll
            for (int ni = 0; ni < 4; ++ni) {
                const int d  = ni * 16 + l15;
                const float val = acc[mi][ni][r] + bn[ni];
                const float pv  = acc[mi][ni ^ 2][r] + bn[ni ^ 2];
                const float cs = cosb[s * HD_ + d];
                const float sn = sinb[s * HD_ + d];
                const float rot = (ni < 2) ? -pv : pv;
                dst[((size_t)(b * NH_ + hw) * S_ + s) * HD_ + d] =
                    (short)f2bf_fast((val * cs + rot * sn) * sc);
            }
        }
}

// ---------------------------------------------------------------------------
// Flash attention, bf16 MFMA 32x32x16, fp32 accum, non-causal.
// R15 change: KVBLK 64 -> 128 (double-buffered, 64 KB LDS).  R13 showed the
// barrier convoy multiplies per-wave VALU cost ~4x and the HW packs only 2
// blocks/CU regardless of LDS (R8/R13 occupancy) — so doubling the KV tile
// halves the number of barrier/convoy events (32 -> 16) at no residency
// cost.  Each period stages 128 kv rows and runs the verified R13 tile body
// twice (half = 0,1; row/col offsets are multiples of 8 so all swizzle keys
// are unchanged).  Everything else identical to R13.
// ---------------------------------------------------------------------------
__global__ __launch_bounds__(256, 2)
void attn_mfma(const short* __restrict__ Q, const short* __restrict__ K,
               const short* __restrict__ Vt, short* __restrict__ AO)
{
    __shared__ short Ks[2][8192];    // [kv=128][d=64] swizzled, 16 KB per buf
    __shared__ short Vs[2][8192];    // [d=64][kv=128] swizzled, 16 KB per buf

    const int t    = threadIdx.x;
    const int lane = t & 63;
    const int wid  = t >> 6;         // 0..3

    // XCD-affine decode (R11/R12-verified): 6 heads per XCD; K/V L2-resident.
    const int bid = blockIdx.x;
    const int xcd = bid & 7;
    const int sq  = bid >> 3;            // 0..95
    const int bh  = xcd * 6 + (sq >> 4); // 0..47
    const int q0  = (sq & 15) * 128;

    const int l31 = lane & 31;
    const int hi  = lane >> 5;
    const int sw7 = lane & 7;        // == row&7 for all frag rows (offsets %8==0)

    const short* Qg = Q  + ((size_t)bh * S_ + q0 + wid*32) * HD_;
    const short* Kg = K  + (size_t)bh * S_ * HD_;
    const short* Vg = Vt + (size_t)bh * HD_ * S_;

    bf16x8 qf[4];
#pragma unroll
    for (int kk = 0; kk < 4; ++kk)
        qf[kk] = *(const bf16x8*)(Qg + (size_t)l31*HD_ + kk*16 + hi*8);

    f32x16 oacc[2];
#pragma unroll
    for (int nt = 0; nt < 2; ++nt)
#pragma unroll
        for (int r = 0; r < 16; ++r) oacc[nt][r] = 0.f;
    float la[4] = {0.f, 0.f, 0.f, 0.f};

    // stage 128 kv rows: K 1024 chunks [kv][d], V 1024 chunks [d][kv=128]
    auto stageKV = [&](int b, int kt) {
#pragma unroll
        for (int cc = 0; cc < 4; ++cc) {
            const int d   = cc * 256 + t;        // 0..1023
            const int row = d >> 3;              // 0..127
            const int sg  = (d & 7) ^ (row & 7); // inverse swizzle on source
            gload16(Kg + (size_t)(kt + row) * HD_ + sg * 8, &Ks[b][d * 8]);
        }
#pragma unroll
        for (int cc = 0; cc < 4; ++cc) {
            const int d   = cc * 256 + t;        // 0..1023
            const int row = d >> 4;              // 0..63
            const int c   = (d & 15) ^ (row & 7);// logical col-chunk (0..15)
            gload16(Vg + (size_t)row * S_ + kt + c * 8, &Vs[b][d * 8]);
        }
    };

    stageKV(0, 0);
    __syncthreads();
    int cur = 0;

    for (int kt = 0; kt < S_; kt += 128) {
        if (kt + 128 < S_) stageKV(cur ^ 1, kt + 128);

#pragma unroll
        for (int half = 0; half < 2; ++half) {
            // S^T = K * Q^T  (scores already in exp2 domain via Q scale)
            f32x16 sac[2];
#pragma unroll
            for (int nt = 0; nt < 2; ++nt)
#pragma unroll
                for (int r = 0; r < 16; ++r) sac[nt][r] = 0.f;
            __builtin_amdgcn_s_setprio(1);
#pragma unroll
            for (int kk = 0; kk < 4; ++kk) {
#pragma unroll
                for (int nt = 0; nt < 2; ++nt) {
                    const int row = half*64 + nt*32 + l31;   // 0..127
                    const bf16x8 kfrag = *(const bf16x8*)
                        &Ks[cur][row*64 + (((kk*2 + hi) ^ sw7) << 3)];
                    sac[nt] = __builtin_amdgcn_mfma_f32_32x32x16_bf16(kfrag, qf[kk], sac[nt], 0, 0, 0);
                }
            }
            __builtin_amdgcn_s_setprio(0);

            // fixed-max softmax: p = 2^s; denominator in 4 parallel partials
#pragma unroll
            for (int nt = 0; nt < 2; ++nt)
#pragma unroll
                for (int r = 0; r < 16; ++r) {
                    sac[nt][r] = fast_exp2(sac[nt][r]);
                    la[r & 3] += sac[nt][r];
                }

            // PV B-frags in-register: 16 cvt_pk_bf16 + 8 permlane32_swap
            unsigned pw[4][4];
#pragma unroll
            for (int kk = 0; kk < 4; ++kk) {
                const int h  = kk >> 1;
                const int g2 = (kk & 1) * 2;
#pragma unroll
                for (int e = 0; e < 2; ++e) {
                    unsigned A = cvt_pk_bf16(sac[h][4*g2     + 2*e], sac[h][4*g2     + 2*e + 1]);
                    unsigned Bv= cvt_pk_bf16(sac[h][4*(g2+1) + 2*e], sac[h][4*(g2+1) + 2*e + 1]);
                    asm volatile("v_permlane32_swap_b32 %0, %1" : "+v"(A), "+v"(Bv));
                    pw[kk][e]     = A;
                    pw[kk][e + 2] = Bv;
                }
            }

            // O^T += V^T * P^T
            __builtin_amdgcn_s_setprio(1);
#pragma unroll
            for (int ks = 0; ks < 4; ++ks) {
                union { unsigned u[4]; bf16x8 v; } pf;
                pf.u[0] = pw[ks][0]; pf.u[1] = pw[ks][1];
                pf.u[2] = pw[ks][2]; pf.u[3] = pw[ks][3];
#pragma unroll
                for (int nt = 0; nt < 2; ++nt) {
                    const int row = nt*32 + l31;             // V row = d, 0..63
                    const int c   = half*8 + ks*2 + hi;      // logical col-chunk
                    const bf16x8 vfrag = *(const bf16x8*)
                        &Vs[cur][row*128 + ((c ^ sw7) << 3)];
                    oacc[nt] = __builtin_amdgcn_mfma_f32_32x32x16_bf16(vfrag, pf.v, oacc[nt], 0, 0, 0);
                }
            }
            __builtin_amdgcn_s_setprio(0);
        }

        __syncthreads();
        cur ^= 1;
    }

    float lacc = (la[0] + la[1]) + (la[2] + la[3]);
    lacc += __shfl_xor(lacc, 32);
    const float inv = 1.f / lacc;

    const int b = bh / NH_, h = bh % NH_;
    const int srow = q0 + wid*32 + l31;
    const size_t rowb = ((size_t)(b*S_ + srow)) * H_ + h*HD_;
#pragma unroll
    for (int nt = 0; nt < 2; ++nt)
#pragma unroll
        for (int i = 0; i < 8; ++i) {
            const int crow = ((2*i) & 3) + 8*((2*i) >> 2) + 4*hi;
            const int d    = nt*32 + crow;
            *(unsigned*)&AO[rowb + d] =
                cvt_pk_bf16(oacc[nt][2*i]*inv, oacc[nt][2*i+1]*inv);
        }
}

// ---------------------------------------------------------------------------
extern "C" void kernel_launch(void* const* d_in, const int* in_sizes, int n_in,
                              void* d_out, int out_size, void* d_ws, size_t ws_size,
                              hipStream_t stream)
{
    const float* X    = (const float*)d_in[0];
    const float* cosb = (const float*)d_in[1];
    const float* sinb = (const float*)d_in[2];
    const float* wq   = (const float*)d_in[3];
    const float* bq   = (const float*)d_in[4];
    const float* wk   = (const float*)d_in[5];
    const float* bk   = (const float*)d_in[6];
    const float* wv   = (const float*)d_in[7];
    const float* bv   = (const float*)d_in[8];
    const float* wo   = (const float*)d_in[9];
    const float* bo   = (const float*)d_in[10];
    float* out = (float*)d_out;

    const size_t MH = (size_t)M_ * H_;      // 6.29M
    const size_t HH = (size_t)H_ * H_;      // 2.36M

    short* Xh  = (short*)d_ws;
    short* Wqh = Xh  + MH;
    short* Wkh = Wqh + HH;
    short* Wvh = Wkh + HH;
    short* Woh = Wvh + HH;
    short* Qb  = Woh + HH;
    short* Kb  = Qb + MH;
    short* Vt  = Kb + MH;
    short* AO  = Vt + MH;

    cast_all<<<(int)(MH/1024 + 4*(HH/1024)), 256, 0, stream>>>(
        X, wq, wk, wv, wo, Xh, Wqh, Wkh, Wvh, Woh);

    gemm_bf16<0><<<1152, 256, 0, stream>>>(Xh, Wqh, Wkh, Wvh,
        bq, bk, bv, cosb, sinb, Qb, Kb, Vt, nullptr);

    attn_mfma<<<768, 256, 0, stream>>>(Qb, Kb, Vt, AO);

    gemm_bf16<1><<<384, 256, 0, stream>>>(AO, Woh, nullptr, nullptr,
        bo, nullptr, nullptr, nullptr, nullptr, nullptr, nullptr, nullptr, out);
}

// Round 16
// 181.075 us; speedup vs baseline: 1.0967x; 1.0571x over previous
//
#include <hip/hip_runtime.h>
#include <hip/hip_bf16.h>
#include <cstdint>

namespace {
constexpr int H_  = 1536;
constexpr int NH_ = 24;
constexpr int HD_ = 64;
constexpr int B_  = 2;
constexpr int S_  = 2048;
constexpr int M_  = B_ * S_;          // 4096
constexpr int KD_ = H_;               // GEMM depth
}

typedef __attribute__((ext_vector_type(8)))  short bf16x8;
typedef __attribute__((ext_vector_type(4)))  float f32x4;
typedef __attribute__((ext_vector_type(16))) float f32x16;

// fp32 -> bf16, round-half-up (2 VALU ops; vs ~5 for RNE emulation)
__device__ __forceinline__ unsigned short f2bf_fast(float x) {
    return (unsigned short)((__float_as_uint(x) + 0x8000u) >> 16);
}
// two fp32 -> packed bf16x2 in a u32 (lo = a, hi = b), round-half-up
__device__ __forceinline__ unsigned pack2bf(float b_hi, float a_lo) {
    const unsigned ub = __float_as_uint(b_hi) + 0x8000u;
    const unsigned ua = __float_as_uint(a_lo) + 0x8000u;
    return (ub & 0xffff0000u) | (ua >> 16);
}
// two fp32 -> packed bf16x2, single HW instr, RNE (T12: no builtin on gfx950)
__device__ __forceinline__ unsigned cvt_pk_bf16(float lo, float hi) {
    unsigned r;
    asm("v_cvt_pk_bf16_f32 %0, %1, %2" : "=v"(r) : "v"(lo), "v"(hi));
    return r;
}

__device__ __forceinline__ float fast_exp2(float x) {
#if __has_builtin(__builtin_amdgcn_exp2f)
    return __builtin_amdgcn_exp2f(x);   // bare v_exp_f32
#else
    return exp2f(x);
#endif
}

__device__ __forceinline__ void gload16(const short* g, short* l) {
    __builtin_amdgcn_global_load_lds(
        (const __attribute__((address_space(1))) unsigned int*)g,
        (__attribute__((address_space(3))) unsigned int*)l, 16, 0, 0);
}

// ---------------------------------------------------------------------------
// Fused fp32 -> bf16 cast for X and the 4 weight matrices (one launch).
// ---------------------------------------------------------------------------
__global__ __launch_bounds__(256)
void cast_all(const float* __restrict__ X,
              const float* __restrict__ wq, const float* __restrict__ wk,
              const float* __restrict__ wv, const float* __restrict__ wo,
              short* __restrict__ Xh,
              short* __restrict__ Wqh, short* __restrict__ Wkh,
              short* __restrict__ Wvh, short* __restrict__ Woh)
{
    constexpr int XB = (M_*H_) / 1024;   // 6144 blocks for X
    constexpr int WB = (H_*H_) / 1024;   // 2304 blocks per weight
    const int bid = blockIdx.x;
    const float* src; short* dst; int off;
    if (bid < XB)            { src = X;  dst = Xh;  off = bid; }
    else {
        const int r = bid - XB, wsel = r / WB; off = r % WB;
        if      (wsel == 0)  { src = wq; dst = Wqh; }
        else if (wsel == 1)  { src = wk; dst = Wkh; }
        else if (wsel == 2)  { src = wv; dst = Wvh; }
        else                 { src = wo; dst = Woh; }
    }
    const int i = (off * 256 + threadIdx.x) * 4;
    const float4 v = *(const float4*)&src[i];
    uint2 o;
    o.x = pack2bf(v.y, v.x);
    o.y = pack2bf(v.w, v.z);
    *(uint2*)&dst[i] = o;
}

// ---------------------------------------------------------------------------
// bf16 GEMM (single pass):  C[M,N] = A[M,K] @ W[N,K]^T + bias, fp32 accum.
// R13 config (proven 74us QKV; R14's BM=256 regressed, R15 confirmed).
// m97-style: tile 128x128, BK=64, single-buffered 32 KB LDS, 2 barriers per
// K-step, global_load_lds w16, inverse XOR swizzle on the GLOBAL source.
// KIND 0 (QKV fused, grid 1152): z=0 Q (rope, scale=0.125*log2e), z=1 K
// (rope), z=2 V (bf16 transposed (b,h,d,s)).  KIND 1 (O-proj): fp32 + bias.
// ---------------------------------------------------------------------------
template<int KIND>
__global__ __launch_bounds__(256, 4)
void gemm_bf16(const short* __restrict__ A_g,
               const short* __restrict__ Wq, const short* __restrict__ Wk,
               const short* __restrict__ Wv,
               const float* __restrict__ bq, const float* __restrict__ bk,
               const float* __restrict__ bv,
               const float* __restrict__ cosb, const float* __restrict__ sinb,
               short* __restrict__ Qb, short* __restrict__ Kb,
               short* __restrict__ Vt, float* __restrict__ outf)
{
    __shared__ short Ah[128*64], Bh[128*64];   // 16 KB each

    const int t    = threadIdx.x;
    const int lane = t & 63;
    const int w    = t >> 6;
    const int wr   = w >> 1, wc = w & 1;
    const int l15  = lane & 15;
    const int grp  = lane >> 4;

    // bijective XCD-aware decode: m fast (4 per XCD), then n, then z
    const int xcd = blockIdx.x & 7;
    const int off = blockIdx.x >> 3;
    const int m_idx = xcd * 4 + (off & 3);
    const int rest  = off >> 2;                  // QKV: 0..35, O: 0..11
    const int n_idx = rest % 12;
    const int zi    = (KIND == 0) ? rest / 12 : 3;

    const int m0 = m_idx * 128;
    const int n0 = n_idx * 128;

    const short* bhg; const float* bias;
    if (KIND == 0) {
        if      (zi == 0) { bhg = Wq; bias = bq; }
        else if (zi == 1) { bhg = Wk; bias = bk; }
        else              { bhg = Wv; bias = bv; }
    } else {
        bhg = Wq; bias = bq;                     // O-proj passes wo/bo here
    }

    f32x4 acc[4][4];
#pragma unroll
    for (int i = 0; i < 4; ++i)
#pragma unroll
        for (int j = 0; j < 4; ++j) acc[i][j] = (f32x4){0.f, 0.f, 0.f, 0.f};

    const int srow  = lane >> 3;
    const int sslot = (lane & 7) ^ srow;

    for (int kt = 0; kt < KD_; kt += 64) {
        __syncthreads();
#pragma unroll
        for (int cc = 0; cc < 4; ++cc) {
            const int c = w * 4 + cc;
            const int r = c * 8 + srow;
            gload16(A_g + (size_t)(m0 + r) * KD_ + kt + sslot * 8, Ah + c * 512);
            gload16(bhg + (size_t)(n0 + r) * KD_ + kt + sslot * 8, Bh + c * 512);
        }
        __syncthreads();

#pragma unroll
        for (int kk = 0; kk < 2; ++kk) {
            bf16x8 af[4], bfr[4];
#pragma unroll
            for (int i = 0; i < 4; ++i) {
                const int ra = wr * 64 + i * 16 + l15;
                af[i]  = *(const bf16x8*)&Ah[ra * 64 + (((kk*4 + grp) ^ (ra & 7)) << 3)];
                const int rb = wc * 64 + i * 16 + l15;
                bfr[i] = *(const bf16x8*)&Bh[rb * 64 + (((kk*4 + grp) ^ (rb & 7)) << 3)];
            }
#pragma unroll
            for (int i = 0; i < 4; ++i)
#pragma unroll
                for (int j = 0; j < 4; ++j)
                    acc[i][j] = __builtin_amdgcn_mfma_f32_16x16x32_bf16(af[i], bfr[j], acc[i][j], 0, 0, 0);
        }
    }

    // ---------------- epilogue ----------------
    float bn[4];
#pragma unroll
    for (int ni = 0; ni < 4; ++ni) bn[ni] = bias[n0 + wc * 64 + ni * 16 + l15];
    const int hw = (n0 + wc * 64) >> 6;          // head (tile 64-aligned)

    if (KIND == 1) {
#pragma unroll
        for (int mi = 0; mi < 4; ++mi)
#pragma unroll
            for (int r = 0; r < 4; ++r) {
                const int m = m0 + wr * 64 + mi * 16 + grp * 4 + r;
#pragma unroll
                for (int ni = 0; ni < 4; ++ni)
                    outf[(size_t)m * H_ + n0 + wc * 64 + ni * 16 + l15] =
                        acc[mi][ni][r] + bn[ni];
            }
        return;
    }

    if (zi == 2) {
        // V: bf16 transposed (b, h, d, s)
        const int b = m0 >> 11;
#pragma unroll
        for (int mi = 0; mi < 4; ++mi) {
            const int sb = (m0 & (S_ - 1)) + wr * 64 + mi * 16 + grp * 4;
#pragma unroll
            for (int ni = 0; ni < 4; ++ni) {
                const int d = ni * 16 + l15;
                uint2 o;
                o.x = pack2bf(acc[mi][ni][1] + bn[ni], acc[mi][ni][0] + bn[ni]);
                o.y = pack2bf(acc[mi][ni][3] + bn[ni], acc[mi][ni][2] + bn[ni]);
                *(uint2*)&Vt[((size_t)(b * NH_ + hw) * HD_ + d) * S_ + sb] = o;
            }
        }
        return;
    }

    // Q/K: rope + scale + bf16 head-major (b,h,s,d); partner d^32 = acc[..][ni^2]
    // Q carries 0.125*log2(e) so attention scores are already in exp2 domain.
    const float sc = (zi == 0) ? 0.18033688011112042f : 1.0f;
    short* dst = (zi == 0) ? Qb : Kb;
#pragma unroll
    for (int mi = 0; mi < 4; ++mi)
#pragma unroll
        for (int r = 0; r < 4; ++r) {
            const int m = m0 + wr * 64 + mi * 16 + grp * 4 + r;
            const int b = m >> 11;
            const int s = m & (S_ - 1);
#pragma unroll
            for (int ni = 0; ni < 4; ++ni) {
                const int d  = ni * 16 + l15;
                const float val = acc[mi][ni][r] + bn[ni];
                const float pv  = acc[mi][ni ^ 2][r] + bn[ni ^ 2];
                const float cs = cosb[s * HD_ + d];
                const float sn = sinb[s * HD_ + d];
                const float rot = (ni < 2) ? -pv : pv;
                dst[((size_t)(b * NH_ + hw) * S_ + s) * HD_ + d] =
                    (short)f2bf_fast((val * cs + rot * sn) * sc);
            }
        }
}

// ---------------------------------------------------------------------------
// Flash attention, bf16 MFMA 32x32x16, fp32 accum, non-causal.
// R16: T15 double-pipeline on the R13 structure (KVBLK=64, proven fastest).
// Per tile, softmax-finish (exp2/cvt_pk/permlane, VALU) of tile t-1 runs
// AFTER issuing tile t's QK MFMAs — independent work on separate pipes, so
// the VALU phase hides under matrix-pipe latency instead of stalling on it.
// 3 LDS buffer slots (48 KB): tile t (QK), t-1 (PV's V), t+1 (staging).
// Race-safety: stage(t+1 -> buf[(t+1)%3]) overwrites tile t-2's slot, whose
// last reader (PV at body t-1) is sealed by body t-1's barrier, which
// precedes the stage in program order.  sacA/sacB ping-pong via manually
// 2x-unrolled body (static register indexing, rule 20).
// Everything else identical to R13 (XCD-affine map, in-register P,
// fixed-max exp2 softmax, 4-way parallel deferred denominator).
// ---------------------------------------------------------------------------
__global__ __launch_bounds__(256, 2)
void attn_mfma(const short* __restrict__ Q, const short* __restrict__ K,
               const short* __restrict__ Vt, short* __restrict__ AO)
{
    __shared__ short Ks[3][4096];    // [kv=64][d=64] swizzled, 8 KB per slot
    __shared__ short Vs[3][4096];    // [d=64][kv=64] swizzled, 8 KB per slot

    const int t    = threadIdx.x;
    const int lane = t & 63;
    const int wid  = t >> 6;         // 0..3

    // XCD-affine decode (R11/R12-verified): 6 heads per XCD; K/V L2-resident.
    const int bid = blockIdx.x;
    const int xcd = bid & 7;
    const int sq  = bid >> 3;            // 0..95
    const int bh  = xcd * 6 + (sq >> 4); // 0..47
    const int q0  = (sq & 15) * 128;

    const int l31 = lane & 31;
    const int hi  = lane >> 5;
    const int sw7 = lane & 7;

    const short* Qg = Q  + ((size_t)bh * S_ + q0 + wid*32) * HD_;
    const short* Kg = K  + (size_t)bh * S_ * HD_;
    const short* Vg = Vt + (size_t)bh * HD_ * S_;

    bf16x8 qf[4];
#pragma unroll
    for (int kk = 0; kk < 4; ++kk)
        qf[kk] = *(const bf16x8*)(Qg + (size_t)l31*HD_ + kk*16 + hi*8);

    f32x16 oacc[2];
#pragma unroll
    for (int nt = 0; nt < 2; ++nt)
#pragma unroll
        for (int r = 0; r < 16; ++r) oacc[nt][r] = 0.f;
    float la[4] = {0.f, 0.f, 0.f, 0.f};

    auto stageKV = [&](int b, int kt) {
#pragma unroll
        for (int cc = 0; cc < 2; ++cc) {
            const int d   = cc * 256 + t;
            const int row = d >> 3;
            const int sg  = (d & 7) ^ (row & 7);
            gload16(Kg + (size_t)(kt + row) * HD_ + sg * 8, &Ks[b][d * 8]);
            gload16(Vg + (size_t)row * S_ + kt + sg * 8,    &Vs[b][d * 8]);
        }
    };

    // QK^T for the tile in LDS slot cb -> sac[0..1]
    auto qkt = [&](int cb, f32x16* sac) {
        sac[0] = (f32x16)(0.f);
        sac[1] = (f32x16)(0.f);
        __builtin_amdgcn_s_setprio(1);
#pragma unroll
        for (int kk = 0; kk < 4; ++kk) {
#pragma unroll
            for (int nt = 0; nt < 2; ++nt) {
                const int row = nt*32 + l31;
                const bf16x8 kfrag = *(const bf16x8*)
                    &Ks[cb][row*64 + (((kk*2 + hi) ^ sw7) << 3)];
                sac[nt] = __builtin_amdgcn_mfma_f32_32x32x16_bf16(kfrag, qf[kk], sac[nt], 0, 0, 0);
            }
        }
        __builtin_amdgcn_s_setprio(0);
    };

    // softmax-finish: exp2 + denominator partials + in-register P frags
    auto sm_pack = [&](f32x16* sac, unsigned (&pw)[4][4]) {
#pragma unroll
        for (int nt = 0; nt < 2; ++nt)
#pragma unroll
            for (int r = 0; r < 16; ++r) {
                sac[nt][r] = fast_exp2(sac[nt][r]);
                la[r & 3] += sac[nt][r];
            }
#pragma unroll
        for (int kk = 0; kk < 4; ++kk) {
            const int h  = kk >> 1;
            const int g2 = (kk & 1) * 2;
#pragma unroll
            for (int e = 0; e < 2; ++e) {
                unsigned A = cvt_pk_bf16(sac[h][4*g2     + 2*e], sac[h][4*g2     + 2*e + 1]);
                unsigned Bv= cvt_pk_bf16(sac[h][4*(g2+1) + 2*e], sac[h][4*(g2+1) + 2*e + 1]);
                asm volatile("v_permlane32_swap_b32 %0, %1" : "+v"(A), "+v"(Bv));
                pw[kk][e]     = A;
                pw[kk][e + 2] = Bv;
            }
        }
    };

    // PV accumulate using V in LDS slot vb
    auto pv = [&](unsigned (&pw)[4][4], int vb) {
        __builtin_amdgcn_s_setprio(1);
#pragma unroll
        for (int ks = 0; ks < 4; ++ks) {
            union { unsigned u[4]; bf16x8 v; } pf;
            pf.u[0] = pw[ks][0]; pf.u[1] = pw[ks][1];
            pf.u[2] = pw[ks][2]; pf.u[3] = pw[ks][3];
#pragma unroll
            for (int nt = 0; nt < 2; ++nt) {
                const int row = nt*32 + l31;
                const bf16x8 vfrag = *(const bf16x8*)
                    &Vs[vb][row*64 + (((ks*2 + hi) ^ sw7) << 3)];
                oacc[nt] = __builtin_amdgcn_mfma_f32_32x32x16_bf16(vfrag, pf.v, oacc[nt], 0, 0, 0);
            }
        }
        __builtin_amdgcn_s_setprio(0);
    };

    // ---- prologue: stage tiles 0,1; QK of tile 0 ----
    stageKV(0, 0);
    stageKV(1, 64);
    __syncthreads();

    f32x16 sacA[2], sacB[2];
    unsigned pw[4][4];
    qkt(0, sacA);

    // ---- main: tiles 1..30 in ping-pong pairs ----
    for (int tp = 1; tp + 1 < 32; tp += 2) {
        {   // body(tp): cur=sacB, prev=sacA
            const int cb = tp % 3, pb = (tp - 1) % 3, nb = (tp + 1) % 3;
            qkt(cb, sacB);
            stageKV(nb, (tp + 1) * 64);
            sm_pack(sacA, pw);
            pv(pw, pb);
            __syncthreads();
        }
        {   // body(tp+1): cur=sacA, prev=sacB
            const int t2 = tp + 1;
            const int cb = t2 % 3, pb = (t2 - 1) % 3, nb = (t2 + 1) % 3;
            qkt(cb, sacA);
            stageKV(nb, (t2 + 1) * 64);
            sm_pack(sacB, pw);
            pv(pw, pb);
            __syncthreads();
        }
    }
    {   // body(31): cur=sacB, prev=sacA; no staging
        qkt(31 % 3, sacB);
        sm_pack(sacA, pw);
        pv(pw, 30 % 3);
    }
    // epilogue: finish tile 31
    sm_pack(sacB, pw);
    pv(pw, 31 % 3);

    // final denominator: combine 4 partials, then cross-half reduce
    float lacc = (la[0] + la[1]) + (la[2] + la[3]);
    lacc += __shfl_xor(lacc, 32);
    const float inv = 1.f / lacc;

    const int b = bh / NH_, h = bh % NH_;
    const int srow = q0 + wid*32 + l31;
    const size_t rowb = ((size_t)(b*S_ + srow)) * H_ + h*HD_;
#pragma unroll
    for (int nt = 0; nt < 2; ++nt)
#pragma unroll
        for (int i = 0; i < 8; ++i) {
            const int crow = ((2*i) & 3) + 8*((2*i) >> 2) + 4*hi;
            const int d    = nt*32 + crow;
            *(unsigned*)&AO[rowb + d] =
                cvt_pk_bf16(oacc[nt][2*i]*inv, oacc[nt][2*i+1]*inv);
        }
}

// ---------------------------------------------------------------------------
extern "C" void kernel_launch(void* const* d_in, const int* in_sizes, int n_in,
                              void* d_out, int out_size, void* d_ws, size_t ws_size,
                              hipStream_t stream)
{
    const float* X    = (const float*)d_in[0];
    const float* cosb = (const float*)d_in[1];
    const float* sinb = (const float*)d_in[2];
    const float* wq   = (const float*)d_in[3];
    const float* bq   = (const float*)d_in[4];
    const float* wk   = (const float*)d_in[5];
    const float* bk   = (const float*)d_in[6];
    const float* wv   = (const float*)d_in[7];
    const float* bv   = (const float*)d_in[8];
    const float* wo   = (const float*)d_in[9];
    const float* bo   = (const float*)d_in[10];
    float* out = (float*)d_out;

    const size_t MH = (size_t)M_ * H_;      // 6.29M
    const size_t HH = (size_t)H_ * H_;      // 2.36M

    short* Xh  = (short*)d_ws;
    short* Wqh = Xh  + MH;
    short* Wkh = Wqh + HH;
    short* Wvh = Wkh + HH;
    short* Woh = Wvh + HH;
    short* Qb  = Woh + HH;
    short* Kb  = Qb + MH;
    short* Vt  = Kb + MH;
    short* AO  = Vt + MH;

    cast_all<<<(int)(MH/1024 + 4*(HH/1024)), 256, 0, stream>>>(
        X, wq, wk, wv, wo, Xh, Wqh, Wkh, Wvh, Woh);

    gemm_bf16<0><<<1152, 256, 0, stream>>>(Xh, Wqh, Wkh, Wvh,
        bq, bk, bv, cosb, sinb, Qb, Kb, Vt, nullptr);

    attn_mfma<<<768, 256, 0, stream>>>(Qb, Kb, Vt, AO);

    gemm_bf16<1><<<384, 256, 0, stream>>>(AO, Woh, nullptr, nullptr,
        bo, nullptr, nullptr, nullptr, nullptr, nullptr, nullptr, nullptr, out);
}